// Round 19
// baseline (233.135 us; speedup 1.0000x reference)
//
#include <hip/hip_runtime.h>
#include <hip/hip_bf16.h>
#include <cstdint>

// ---------- problem constants ----------
constexpr int Bc  = 2;
constexpr int Sc  = 2048;
constexpr int Dc  = 1024;
constexpr int Hc  = 16;
constexpr int DKc = 64;
constexpr int DFFc= 4096;
constexpr int BSc = Bc * Sc;      // 4096 rows

typedef __attribute__((ext_vector_type(8))) short bf16x8;
typedef __attribute__((ext_vector_type(4))) float f32x4;

__device__ __forceinline__ unsigned short f2bf(float x){
  union { float f; uint32_t u; } v; v.f = x;
  uint32_t r = v.u + 0x7fffu + ((v.u >> 16) & 1u);   // RNE
  return (unsigned short)(r >> 16);
}

__device__ __forceinline__ void gload16(const void* g, void* l){
  __builtin_amdgcn_global_load_lds((const __attribute__((address_space(1))) void*)g,
                                   (__attribute__((address_space(3))) void*)l, 16, 0, 0);
}

__device__ __forceinline__ f32x4 mfma16(bf16x8 a, bf16x8 b, f32x4 c){
  return __builtin_amdgcn_mfma_f32_16x16x32_bf16(a, b, c, 0, 0, 0);
}

// pack two f32 -> one u32 of 2x bf16 (v_cvt_pk_bf16_f32)
__device__ __forceinline__ uint32_t pk2bf(float lo, float hi){
  __hip_bfloat162 h = __float22bfloat162_rn(make_float2(lo, hi));
  return *reinterpret_cast<uint32_t*>(&h);
}

// raw v_exp_f32: r = 2^x
__device__ __forceinline__ float fexp2(float x){
  float r; asm("v_exp_f32 %0, %1" : "=v"(r) : "v"(x)); return r;
}

// bijective XCD swizzle (T1, m204 form)
__device__ __forceinline__ int xcd_swz(int bid, int nwg){
  const int q = nwg >> 3, r = nwg & 7;
  const int xcd = bid & 7, idx = bid >> 3;
  return ((xcd < r) ? (xcd * (q + 1)) : (r * (q + 1) + (xcd - r) * q)) + idx;
}

// ---------- fused prep: 6 weight transposes (f32[K][N] -> bf16[N][K]) + bias concat ----------
__global__ __launch_bounds__(256)
void prep_all(const float* __restrict__ wq, const float* __restrict__ wk,
              const float* __restrict__ wv, const float* __restrict__ wo,
              const float* __restrict__ w1, const float* __restrict__ w2,
              const float* __restrict__ bq, const float* __restrict__ bk,
              const float* __restrict__ bv,
              unsigned short* __restrict__ wqkv_t, unsigned short* __restrict__ wo_t,
              unsigned short* __restrict__ w1_t, unsigned short* __restrict__ w2_t,
              float* __restrict__ bqkv){
  const int id = blockIdx.x, tid = threadIdx.x;
  if (id >= 12288){                      // concat_bias: 12 blocks x 256 = 3072
    const int i = (id - 12288) * 256 + tid;
    bqkv[i] = (i < 1024) ? bq[i] : (i < 2048 ? bk[i - 1024] : bv[i - 2048]);
    return;
  }
  const float* in; unsigned short* out; int K, N, bx, by;
  if (id < 4096){
    const int w = id >> 10, local = id & 1023;
    in  = (w == 0) ? wq : (w == 1) ? wk : (w == 2) ? wv : wo;
    out = (w == 0) ? wqkv_t : (w == 1) ? (wqkv_t + 1048576) : (w == 2) ? (wqkv_t + 2097152) : wo_t;
    K = 1024; N = 1024; bx = local & 31; by = local >> 5;
  } else if (id < 8192){
    const int local = id - 4096;
    in = w1; out = w1_t; K = 1024; N = 4096; bx = local & 127; by = local >> 7;
  } else {
    const int local = id - 8192;
    in = w2; out = w2_t; K = 4096; N = 1024; bx = local & 31; by = local >> 5;
  }
  __shared__ float t[32][33];
  const int tx = tid & 31, ty = tid >> 5;
  const int x0 = bx * 32, y0 = by * 32;
#pragma unroll
  for (int j = ty; j < 32; j += 8) t[j][tx] = in[(long)(y0 + j) * N + x0 + tx];
  __syncthreads();
#pragma unroll
  for (int j = ty; j < 32; j += 8)
    out[(long)(x0 + j) * K + y0 + tx] = f2bf(t[tx][j]);
}

// mask (int 0/1) -> exp2-domain additive bias: 0 or -1e9*log2(e)
__global__ __launch_bounds__(256)
void mask_addend(const int* __restrict__ mask, float* __restrict__ madd){
  int i = blockIdx.x * 256 + threadIdx.x;   // 0..4095
  madd[i] = (mask[i] != 0) ? 0.f : -1.442695e9f;
}

// ---------- layernorm (ddof=1, eps on std, scalar alpha/beta) f32 -> bf16 ----------
__global__ __launch_bounds__(256)
void layernorm_k(const float* __restrict__ x, const float* __restrict__ al,
                 const float* __restrict__ be, unsigned short* __restrict__ out){
  const int row = blockIdx.x, tid = threadIdx.x;
  const float4 v = ((const float4*)(x + (long)row * Dc))[tid];
  float s  = v.x + v.y + v.z + v.w;
  float ss = v.x*v.x + v.y*v.y + v.z*v.z + v.w*v.w;
#pragma unroll
  for (int d = 1; d < 64; d <<= 1){ s += __shfl_xor(s, d, 64); ss += __shfl_xor(ss, d, 64); }
  __shared__ float red[8];
  const int wid = tid >> 6, lane = tid & 63;
  if (lane == 0){ red[wid*2] = s; red[wid*2+1] = ss; }
  __syncthreads();
  s  = red[0] + red[2] + red[4] + red[6];
  ss = red[1] + red[3] + red[5] + red[7];
  const float mean = s * (1.f / 1024.f);
  float var = (ss - s * mean) * (1.f / 1023.f);
  var = fmaxf(var, 0.f);
  const float k = al[0] / (sqrtf(var) + 1e-6f);
  const float g = be[0];
  ushort4 o;
  o.x = f2bf((v.x - mean) * k + g);
  o.y = f2bf((v.y - mean) * k + g);
  o.z = f2bf((v.z - mean) * k + g);
  o.w = f2bf((v.w - mean) * k + g);
  ((ushort4*)(out + (long)row * Dc))[tid] = o;
}

// ============ 256x256 GEMM, BK=64, 8 waves (2Mx4N), 4-phase fine interleave ============
template<int RELU, int OUTBF16, int RES, int VOUT>
__global__ __launch_bounds__(512, 2)
void gemm256(const unsigned short* __restrict__ A, const unsigned short* __restrict__ BT,
             const float* __restrict__ bias, const float* __restrict__ resid,
             void* __restrict__ Cout, unsigned short* __restrict__ vtw,
             int M, int N, int K){
  __shared__ unsigned short As[2][256 * 64];
  __shared__ unsigned short Bs[2][256 * 64];
  const int tid = threadIdx.x, wid = tid >> 6, lane = tid & 63;
  const int lg = lane >> 4, lr = lane & 15;
  const int wm = wid >> 2, wn = wid & 3;
  const int nwg = gridDim.x * gridDim.y;
  const int wg  = xcd_swz(blockIdx.y * gridDim.x + blockIdx.x, nwg);
  const int bx = wg % gridDim.x, by = wg / gridDim.x;
  const int m0 = by * 256, n0 = bx * 256;
  const long ldA = (long)K * 2;
  const f32x4 zero4 = {0.f, 0.f, 0.f, 0.f};
  f32x4 acc[8][4];
#pragma unroll
  for (int i = 0; i < 8; i++)
#pragma unroll
    for (int j = 0; j < 4; j++) acc[i][j] = zero4;

  auto stage_half = [&](int b, int kt, int h){
    const unsigned short* src = (h < 2) ? A : BT;
    const int rowg = ((h < 2) ? m0 : n0) + (h & 1) * 128;
    char* dst = ((h < 2) ? (char*)As[b] : (char*)Bs[b]) + (h & 1) * 16384;
#pragma unroll
    for (int l = 0; l < 2; ++l){
      const int ob = (wid*2 + l) * 1024;
      const int o  = ob + lane * 16;
      const int rr = o >> 7, c = (o >> 4) & 7;
      const long co = (long)kt * 128 + ((c ^ (rr & 7)) << 4);
      gload16((const char*)src + (long)(rowg + rr) * ldA + co, dst + ob);
    }
  };

  const int nt = K >> 6;
#pragma unroll
  for (int h = 0; h < 4; ++h) stage_half(0, 0, h);
  __syncthreads();   // tile 0 landed (prologue only)

  int cur = 0;
  for (int t = 0; t < nt; ++t){
    const char* as = (const char*)As[cur];
    const char* bs = (const char*)Bs[cur];
    bf16x8 bfr[4][2];
#pragma unroll
    for (int p = 0; p < 4; ++p){
      if (p == 0){
#pragma unroll
        for (int ni = 0; ni < 4; ++ni){
          const int row = wn*64 + ni*16 + lr;
#pragma unroll
          for (int ks = 0; ks < 2; ++ks)
            bfr[ni][ks] = *reinterpret_cast<const bf16x8*>(bs + row*128 + (((ks*4 + lg) ^ (row & 7)) << 4));
        }
      }
      bf16x8 af[2][2];
#pragma unroll
      for (int i = 0; i < 2; ++i){
        const int arow = wm*128 + (2*p + i)*16 + lr;
        af[i][0] = *reinterpret_cast<const bf16x8*>(as + arow*128 + (((0*4 + lg) ^ (arow & 7)) << 4));
        af[i][1] = *reinterpret_cast<const bf16x8*>(as + arow*128 + (((1*4 + lg) ^ (arow & 7)) << 4));
      }
      if (t + 1 < nt) stage_half(cur ^ 1, t + 1, p);
      __builtin_amdgcn_sched_barrier(0);
      __builtin_amdgcn_s_barrier();
      asm volatile("s_waitcnt lgkmcnt(0)" ::: "memory");
      __builtin_amdgcn_sched_barrier(0);
      __builtin_amdgcn_s_setprio(1);
#pragma unroll
      for (int i = 0; i < 2; ++i){
        const int mi = 2*p + i;
#pragma unroll
        for (int ni = 0; ni < 4; ++ni){
          acc[mi][ni] = mfma16(af[i][0], bfr[ni][0], acc[mi][ni]);
          acc[mi][ni] = mfma16(af[i][1], bfr[ni][1], acc[mi][ni]);
        }
      }
      __builtin_amdgcn_s_setprio(0);
      __builtin_amdgcn_sched_barrier(0);
      __builtin_amdgcn_s_barrier();
    }
    if (t + 1 < nt){
      asm volatile("s_waitcnt vmcnt(0)" ::: "memory");
      __builtin_amdgcn_s_barrier();
      __builtin_amdgcn_sched_barrier(0);
    }
    cur ^= 1;
  }

  if (VOUT && n0 >= 2048){
#pragma unroll
    for (int mi = 0; mi < 8; ++mi){
      const int row = m0 + wm*128 + mi*16 + lg*4;   // 4 consecutive rows (same batch)
      const int b = row >> 11, s = row & 2047;
#pragma unroll
      for (int ni = 0; ni < 4; ++ni){
        const int col = n0 + wn*64 + ni*16 + lr;
        const float bc = bias[col];
        ushort4 o;
        o.x = f2bf(acc[mi][ni][0] + bc);
        o.y = f2bf(acc[mi][ni][1] + bc);
        o.z = f2bf(acc[mi][ni][2] + bc);
        o.w = f2bf(acc[mi][ni][3] + bc);
        *(ushort4*)(vtw + ((long)(b * 1024 + (col - 2048)) << 11) + s) = o;
      }
    }
    return;
  }

#pragma unroll
  for (int mi = 0; mi < 8; ++mi)
#pragma unroll
    for (int ni = 0; ni < 4; ++ni){
      const int col = n0 + wn*64 + ni*16 + lr;
      const float bc = bias[col];
#pragma unroll
      for (int r = 0; r < 4; ++r){
        const int row = m0 + wm*128 + mi*16 + lg*4 + r;
        float v = acc[mi][ni][r] + bc;
        if (RES)  v += resid[(long)row * N + col];
        if (RELU) v = fmaxf(v, 0.f);
        if (OUTBF16) ((unsigned short*)Cout)[(long)row * N + col] = f2bf(v);
        else         ((float*)Cout)[(long)row * N + col] = v;
      }
    }
}

// ============ 128x64 GEMM, BK=64, 8 waves (4Mx2N, 32x32/wave), counted-vmcnt dbuf ============
template<int RELU, int OUTBF16, int RES>
__global__ __launch_bounds__(512, 2)
void gemm12864(const unsigned short* __restrict__ A, const unsigned short* __restrict__ BT,
               const float* __restrict__ bias, const float* __restrict__ resid,
               void* __restrict__ Cout, int M, int N, int K){
  __shared__ unsigned short As[2][128 * 64];
  __shared__ unsigned short Bs[2][64 * 64];
  const int tid = threadIdx.x, wid = tid >> 6, lane = tid & 63;
  const int lg = lane >> 4, lr = lane & 15;
  const int wm = wid >> 1, wn = wid & 1;
  const int nwg = gridDim.x * gridDim.y;
  const int wg  = xcd_swz(blockIdx.y * gridDim.x + blockIdx.x, nwg);
  const int bx = wg % gridDim.x, by = wg / gridDim.x;
  const int m0 = by * 128, n0 = bx * 64;
  const long ldA = (long)K * 2;
  const f32x4 zero4 = {0.f, 0.f, 0.f, 0.f};
  f32x4 acc[2][2];
#pragma unroll
  for (int i = 0; i < 2; i++)
#pragma unroll
    for (int j = 0; j < 2; j++) acc[i][j] = zero4;

  auto stage = [&](int b, int kt){      // 3 gload16 per wave (2 A-chunks + 1 B-chunk)
#pragma unroll
    for (int l = 0; l < 2; ++l){
      const int ob = (wid*2 + l) * 1024;     // A: 16KB = 16 chunks
      const int o  = ob + lane * 16;
      const int rr = o >> 7, c = (o >> 4) & 7;
      const long co = (long)kt * 128 + ((c ^ (rr & 7)) << 4);
      gload16((const char*)A + (long)(m0 + rr) * ldA + co, (char*)As[b] + ob);
    }
    {
      const int ob = wid * 1024;             // B: 8KB = 8 chunks
      const int o  = ob + lane * 16;
      const int rr = o >> 7, c = (o >> 4) & 7;
      const long co = (long)kt * 128 + ((c ^ (rr & 7)) << 4);
      gload16((const char*)BT + (long)(n0 + rr) * ldA + co, (char*)Bs[b] + ob);
    }
  };

  const int nt = K >> 6;
  stage(0, 0);
  stage(1, 1);

  int cur = 0;
  for (int t = 0; t < nt; ++t){
    if (t + 1 < nt) asm volatile("s_waitcnt vmcnt(3)" ::: "memory");
    else            asm volatile("s_waitcnt vmcnt(0)" ::: "memory");
    __builtin_amdgcn_s_barrier();
    __builtin_amdgcn_sched_barrier(0);
    const char* as = (const char*)As[cur];
    const char* bs = (const char*)Bs[cur];
    bf16x8 bfr[2][2];
#pragma unroll
    for (int ni = 0; ni < 2; ++ni){
      const int row = wn*32 + ni*16 + lr;
#pragma unroll
      for (int ks = 0; ks < 2; ++ks)
        bfr[ni][ks] = *reinterpret_cast<const bf16x8*>(bs + row*128 + (((ks*4 + lg) ^ (row & 7)) << 4));
    }
    __builtin_amdgcn_s_setprio(1);
#pragma unroll
    for (int mi = 0; mi < 2; ++mi){
      const int arow = wm*32 + mi*16 + lr;
      bf16x8 a0 = *reinterpret_cast<const bf16x8*>(as + arow*128 + (((0*4 + lg) ^ (arow & 7)) << 4));
      bf16x8 a1 = *reinterpret_cast<const bf16x8*>(as + arow*128 + (((1*4 + lg) ^ (arow & 7)) << 4));
#pragma unroll
      for (int ni = 0; ni < 2; ++ni){
        acc[mi][ni] = mfma16(a0, bfr[ni][0], acc[mi][ni]);
        acc[mi][ni] = mfma16(a1, bfr[ni][1], acc[mi][ni]);
      }
    }
    __builtin_amdgcn_s_setprio(0);
    __builtin_amdgcn_s_barrier();
    __builtin_amdgcn_sched_barrier(0);
    if (t + 2 < nt) stage(cur, t + 2);
    cur ^= 1;
  }

#pragma unroll
  for (int mi = 0; mi < 2; ++mi)
#pragma unroll
    for (int ni = 0; ni < 2; ++ni){
      const int col = n0 + wn*32 + ni*16 + lr;
      const float bc = bias[col];
#pragma unroll
      for (int r = 0; r < 4; ++r){
        const int row = m0 + wm*32 + mi*16 + lg*4 + r;
        float v = acc[mi][ni][r] + bc;
        if (RES)  v += resid[(long)row * N + col];
        if (RELU) v = fmaxf(v, 0.f);
        if (OUTBF16) ((unsigned short*)Cout)[(long)row * N + col] = f2bf(v);
        else         ((float*)Cout)[(long)row * N + col] = v;
      }
    }
}

// ---------- flash attention: QBLK=64 (4 waves), KVBLK=64, swapped QK^T ----------
// Same per-wave work as QBLK=128 (each wave owns 16 q-rows), but: 4-wave barrier
// domains (faster rendezvous) and 4 independent blocks/CU (LDS = QP8+K2x8+V2x8
// = 40KB -> 4 blocks/CU exactly) to fill barrier stalls. K/V re-read from L2
// (bh-clustered working set still 2MB/XCD). Qs/Ps union; issue-early dbuf;
// no running max; exp2-domain masked softmax; l via ones-MFMA.
__global__ __launch_bounds__(256)
void attn_k(const unsigned short* __restrict__ qkv, const unsigned short* __restrict__ vt,
            const float* __restrict__ madd, unsigned short* __restrict__ ctx){
  __shared__ unsigned short QP[64*64], Ks[2][64*64], Vs[2][64*64];
  const int tid = threadIdx.x, wid = tid >> 6, lane = tid & 63;
  const int lg = lane >> 4, lr = lane & 15;
  // bh-clustered block mapping (bijective over 1024 blocks): xcd serves bh in [xcd*4, xcd*4+4)
  const int f   = blockIdx.y * gridDim.x + blockIdx.x;
  const int xcd = f & 7, j = f >> 3;
  const int bh  = (xcd << 2) | (j & 3);
  const int qt  = j >> 2;                 // 0..31
  const int b = bh >> 4, h = bh & 15;
  const int s0 = qt * 64;
  const f32x4 zero4 = {0.f, 0.f, 0.f, 0.f};
  const short onebf = (short)0x3F80;
  const bf16x8 ones = {onebf, onebf, onebf, onebf, onebf, onebf, onebf, onebf};
  const float c1 = 0.18033688f;   // 0.125 * log2(e)

  const char* kbase = (const char*)qkv + (long)(b*Sc) * 6144 + 2048 + h * 128;
  const char* vbase = (const char*)vt + (long)bh * 64 * 4096;
  const float* mrow = madd + b * Sc;
  unsigned short* pb = QP + wid * 1024;   // wave-private 16x64 P strip = this wave's Q rows

  // stage K and V tile t (8KB each): 2+2 gload16 per wave (4 waves)
  auto stageKV = [&](int t, int bsel){
#pragma unroll
    for (int l = 0; l < 2; ++l){
      const int o = (wid*2 + l) * 1024;
      const int ol = o + lane * 16;
      const int r = ol >> 7, c = (ol >> 4) & 7;
      const int sw = ((c ^ (r & 7)) << 4);
      gload16(kbase + (long)(t*64 + r) * 6144 + sw, (char*)Ks[bsel] + o);
      gload16(vbase + (long)r * 4096 + t*128 + sw, (char*)Vs[bsel] + o);
    }
  };

  // prologue: stage Q (8KB = 2 gload16/wave; swizzled source) + K/V tile 0
  const char* qbase = (const char*)qkv + ((long)(b*Sc + s0)) * 6144 + h * 128;
#pragma unroll
  for (int ld = 0; ld < 2; ++ld){
    const int o = (wid*2 + ld) * 1024;
    const int ol = o + lane * 16;
    const int r = ol >> 7, c = (ol >> 4) & 7;
    gload16(qbase + (long)r * 6144 + ((c ^ (r & 7)) << 4), (char*)QP + o);
  }
  stageKV(0, 0);
  float4 ma[4];
#pragma unroll
  for (int ni = 0; ni < 4; ++ni) ma[ni] = *(const float4*)(mrow + ni*16 + lg*4);
  __syncthreads();
  // Q -> regs (each wave reads only its own rows wid*16..+15, which later become its P strip)
  bf16x8 qb[2];
#pragma unroll
  for (int ks = 0; ks < 2; ++ks){
    const int row = wid*16 + lr;
    qb[ks] = *reinterpret_cast<const bf16x8*>((const char*)QP + row*128 + (((ks*4 + lg) ^ (row & 7)) << 4));
  }

  f32x4 acc[4] = {zero4, zero4, zero4, zero4};
  f32x4 accS = zero4;
  constexpr int NT = Sc / 64;

  for (int t = 0; t < NT; ++t){
    if (t){
      asm volatile("s_waitcnt vmcnt(0)" ::: "memory");
      __builtin_amdgcn_s_barrier();
      __builtin_amdgcn_sched_barrier(0);
    }
    if (t + 1 < NT) stageKV(t + 1, (t + 1) & 1);
    float4 man[4];
    if (t + 1 < NT){
#pragma unroll
      for (int ni = 0; ni < 4; ++ni) man[ni] = *(const float4*)(mrow + (t+1)*64 + ni*16 + lg*4);
    }

    const int cur = t & 1;
    const char* ksb = (const char*)Ks[cur];
    const char* vsb = (const char*)Vs[cur];

    f32x4 s4[4];
    __builtin_amdgcn_s_setprio(1);
#pragma unroll
    for (int ni = 0; ni < 4; ++ni){
      s4[ni] = zero4;
      const int row = ni*16 + lr;
#pragma unroll
      for (int ks = 0; ks < 2; ++ks){
        bf16x8 ak = *reinterpret_cast<const bf16x8*>(ksb + row*128 + (((ks*4 + lg) ^ (lr & 7)) << 4));
        s4[ni] = mfma16(ak, qb[ks], s4[ni]);
      }
    }
    __builtin_amdgcn_s_setprio(0);

    float p[4][4];
#pragma unroll
    for (int ni = 0; ni < 4; ++ni){
      p[ni][0] = fexp2(fmaf(s4[ni][0], c1, ma[ni].x));
      p[ni][1] = fexp2(fmaf(s4[ni][1], c1, ma[ni].y));
      p[ni][2] = fexp2(fmaf(s4[ni][2], c1, ma[ni].z));
      p[ni][3] = fexp2(fmaf(s4[ni][3], c1, ma[ni].w));
    }

#pragma unroll
    for (int ni = 0; ni < 4; ++ni){
      uint2 w;
      w.x = pk2bf(p[ni][0], p[ni][1]);
      w.y = pk2bf(p[ni][2], p[ni][3]);
      const int c = ni*2 + (lg >> 1);
      char* dst = (char*)pb + lr*128 + ((c ^ (lr & 7)) << 4) + (lg & 1) * 8;
      *(uint2*)dst = w;
    }
    bf16x8 pa[2];
#pragma unroll
    for (int ks = 0; ks < 2; ++ks){
      pa[ks] = *reinterpret_cast<const bf16x8*>((const char*)pb + lr*128 + (((ks*4 + lg) ^ (lr & 7)) << 4));
    }
    __builtin_amdgcn_s_setprio(1);
#pragma unroll
    for (int ks = 0; ks < 2; ++ks) accS = mfma16(pa[ks], ones, accS);
#pragma unroll
    for (int ni = 0; ni < 4; ++ni){
      const int row = ni*16 + lr;
#pragma unroll
      for (int ks = 0; ks < 2; ++ks){
        bf16x8 bv8 = *reinterpret_cast<const bf16x8*>(vsb + row*128 + (((ks*4 + lg) ^ (lr & 7)) << 4));
        acc[ni] = mfma16(pa[ks], bv8, acc[ni]);
      }
    }
    __builtin_amdgcn_s_setprio(0);
    if (t + 1 < NT){
#pragma unroll
      for (int ni = 0; ni < 4; ++ni) ma[ni] = man[ni];
    }
  }
#pragma unroll
  for (int ni = 0; ni < 4; ++ni){
    const int col = h*64 + ni*16 + lr;
#pragma unroll
    for (int r = 0; r < 4; ++r){
      const int row = s0 + wid*16 + lg*4 + r;
      ctx[(long)(b*Sc + row) * Dc + col] = f2bf(acc[ni][r] / accS[r]);
    }
  }
}

// ---------- host ----------
extern "C" void kernel_launch(void* const* d_in, const int* in_sizes, int n_in,
                              void* d_out, int out_size, void* d_ws, size_t ws_size,
                              hipStream_t stream){
  const float* x  = (const float*)d_in[0];
  const int* mask = (const int*)d_in[1];
  const float* wq = (const float*)d_in[2];
  const float* bq = (const float*)d_in[3];
  const float* wk = (const float*)d_in[4];
  const float* bk = (const float*)d_in[5];
  const float* wv = (const float*)d_in[6];
  const float* bv = (const float*)d_in[7];
  const float* wo = (const float*)d_in[8];
  const float* bo = (const float*)d_in[9];
  const float* w1 = (const float*)d_in[10];
  const float* b1 = (const float*)d_in[11];
  const float* w2 = (const float*)d_in[12];
  const float* b2 = (const float*)d_in[13];
  const float* a1 = (const float*)d_in[14];
  const float* g1 = (const float*)d_in[15];
  const float* a2 = (const float*)d_in[16];
  const float* g2 = (const float*)d_in[17];

  if (ws_size < 75509760u) return;   // workspace layout below needs ~75.5 MB

  char* ws = (char*)d_ws;
  unsigned short* wqkv_t = (unsigned short*)(ws + 0);          // [3072][1024]
  unsigned short* wo_t   = (unsigned short*)(ws + 6291456);    // [1024][1024]
  unsigned short* w1_t   = (unsigned short*)(ws + 8388608);    // [4096][1024]
  unsigned short* w2_t   = (unsigned short*)(ws + 16777216);   // [1024][4096]
  float*          bqkv   = (float*)(ws + 25165824);            // [3072]
  unsigned short* nbuf   = (unsigned short*)(ws + 25178112);   // [4096][1024] (n1 then n2)
  float*          maddf  = (float*)(ws + 25178112);            // [2][2048] — aliases nbuf (dead during attn)
  unsigned short* qkv    = (unsigned short*)(ws + 33566720);   // [4096][3072] (V third unused)
  unsigned short* ff1    = (unsigned short*)(ws + 33566720);   // [4096][4096] (reuses qkv+vt)
  unsigned short* vt     = (unsigned short*)(ws + 58732544);   // [32][64][2048]
  unsigned short* ctx    = (unsigned short*)(ws + 67121152);   // [4096][1024]
  float* x2 = (float*)d_out;                                   // [4096][1024] f32

  prep_all<<<12300, 256, 0, stream>>>(wq, wk, wv, wo, w1, w2, bq, bk, bv,
                                      wqkv_t, wo_t, w1_t, w2_t, bqkv);

  layernorm_k<<<BSc, 256, 0, stream>>>(x, a1, g1, nbuf);
  gemm256<0,1,0,1><<<dim3(12, 16), 512, 0, stream>>>(nbuf, wqkv_t, bqkv, nullptr, qkv, vt, BSc, 3072, 1024);
  mask_addend<<<16, 256, 0, stream>>>(mask, maddf);   // nbuf dead from here until LN2
  attn_k<<<dim3(32, 32), 256, 0, stream>>>(qkv, vt, maddf, ctx);
  gemm12864<0,0,1><<<dim3(16, 32), 512, 0, stream>>>(ctx, wo_t, bo, x, x2, BSc, 1024, 1024);
  layernorm_k<<<BSc, 256, 0, stream>>>(x2, a2, g2, nbuf);
  gemm256<1,1,0,0><<<dim3(16, 16), 512, 0, stream>>>(nbuf, w1_t, b1, nullptr, ff1, nullptr, BSc, 4096, 1024);
  gemm12864<0,0,1><<<dim3(16, 32), 512, 0, stream>>>(ff1, w2_t, b2, x2, d_out, BSc, 1024, 4096);
}

// Round 20
// 220.608 us; speedup vs baseline: 1.0568x; 1.0568x over previous
//
#include <hip/hip_runtime.h>
#include <hip/hip_bf16.h>
#include <cstdint>

// ---------- problem constants ----------
constexpr int Bc  = 2;
constexpr int Sc  = 2048;
constexpr int Dc  = 1024;
constexpr int Hc  = 16;
constexpr int DKc = 64;
constexpr int DFFc= 4096;
constexpr int BSc = Bc * Sc;      // 4096 rows

typedef __attribute__((ext_vector_type(8))) short bf16x8;
typedef __attribute__((ext_vector_type(4))) float f32x4;

__device__ __forceinline__ unsigned short f2bf(float x){
  union { float f; uint32_t u; } v; v.f = x;
  uint32_t r = v.u + 0x7fffu + ((v.u >> 16) & 1u);   // RNE
  return (unsigned short)(r >> 16);
}

__device__ __forceinline__ void gload16(const void* g, void* l){
  __builtin_amdgcn_global_load_lds((const __attribute__((address_space(1))) void*)g,
                                   (__attribute__((address_space(3))) void*)l, 16, 0, 0);
}

__device__ __forceinline__ f32x4 mfma16(bf16x8 a, bf16x8 b, f32x4 c){
  return __builtin_amdgcn_mfma_f32_16x16x32_bf16(a, b, c, 0, 0, 0);
}

// pack two f32 -> one u32 of 2x bf16 (v_cvt_pk_bf16_f32)
__device__ __forceinline__ uint32_t pk2bf(float lo, float hi){
  __hip_bfloat162 h = __float22bfloat162_rn(make_float2(lo, hi));
  return *reinterpret_cast<uint32_t*>(&h);
}

// raw v_exp_f32: r = 2^x
__device__ __forceinline__ float fexp2(float x){
  float r; asm("v_exp_f32 %0, %1" : "=v"(r) : "v"(x)); return r;
}

// bijective XCD swizzle (T1, m204 form)
__device__ __forceinline__ int xcd_swz(int bid, int nwg){
  const int q = nwg >> 3, r = nwg & 7;
  const int xcd = bid & 7, idx = bid >> 3;
  return ((xcd < r) ? (xcd * (q + 1)) : (r * (q + 1) + (xcd - r) * q)) + idx;
}

// ---------- fused prep: 6 weight transposes (f32[K][N] -> bf16[N][K]) + bias concat ----------
__global__ __launch_bounds__(256)
void prep_all(const float* __restrict__ wq, const float* __restrict__ wk,
              const float* __restrict__ wv, const float* __restrict__ wo,
              const float* __restrict__ w1, const float* __restrict__ w2,
              const float* __restrict__ bq, const float* __restrict__ bk,
              const float* __restrict__ bv,
              unsigned short* __restrict__ wqkv_t, unsigned short* __restrict__ wo_t,
              unsigned short* __restrict__ w1_t, unsigned short* __restrict__ w2_t,
              float* __restrict__ bqkv){
  const int id = blockIdx.x, tid = threadIdx.x;
  if (id >= 12288){                      // concat_bias: 12 blocks x 256 = 3072
    const int i = (id - 12288) * 256 + tid;
    bqkv[i] = (i < 1024) ? bq[i] : (i < 2048 ? bk[i - 1024] : bv[i - 2048]);
    return;
  }
  const float* in; unsigned short* out; int K, N, bx, by;
  if (id < 4096){
    const int w = id >> 10, local = id & 1023;
    in  = (w == 0) ? wq : (w == 1) ? wk : (w == 2) ? wv : wo;
    out = (w == 0) ? wqkv_t : (w == 1) ? (wqkv_t + 1048576) : (w == 2) ? (wqkv_t + 2097152) : wo_t;
    K = 1024; N = 1024; bx = local & 31; by = local >> 5;
  } else if (id < 8192){
    const int local = id - 4096;
    in = w1; out = w1_t; K = 1024; N = 4096; bx = local & 127; by = local >> 7;
  } else {
    const int local = id - 8192;
    in = w2; out = w2_t; K = 4096; N = 1024; bx = local & 31; by = local >> 5;
  }
  __shared__ float t[32][33];
  const int tx = tid & 31, ty = tid >> 5;
  const int x0 = bx * 32, y0 = by * 32;
#pragma unroll
  for (int j = ty; j < 32; j += 8) t[j][tx] = in[(long)(y0 + j) * N + x0 + tx];
  __syncthreads();
#pragma unroll
  for (int j = ty; j < 32; j += 8)
    out[(long)(x0 + j) * K + y0 + tx] = f2bf(t[tx][j]);
}

// mask (int 0/1) -> exp2-domain additive bias: 0 or -1e9*log2(e)
__global__ __launch_bounds__(256)
void mask_addend(const int* __restrict__ mask, float* __restrict__ madd){
  int i = blockIdx.x * 256 + threadIdx.x;   // 0..4095
  madd[i] = (mask[i] != 0) ? 0.f : -1.442695e9f;
}

// ---------- layernorm (ddof=1, eps on std, scalar alpha/beta) f32 -> bf16 ----------
__global__ __launch_bounds__(256)
void layernorm_k(const float* __restrict__ x, const float* __restrict__ al,
                 const float* __restrict__ be, unsigned short* __restrict__ out){
  const int row = blockIdx.x, tid = threadIdx.x;
  const float4 v = ((const float4*)(x + (long)row * Dc))[tid];
  float s  = v.x + v.y + v.z + v.w;
  float ss = v.x*v.x + v.y*v.y + v.z*v.z + v.w*v.w;
#pragma unroll
  for (int d = 1; d < 64; d <<= 1){ s += __shfl_xor(s, d, 64); ss += __shfl_xor(ss, d, 64); }
  __shared__ float red[8];
  const int wid = tid >> 6, lane = tid & 63;
  if (lane == 0){ red[wid*2] = s; red[wid*2+1] = ss; }
  __syncthreads();
  s  = red[0] + red[2] + red[4] + red[6];
  ss = red[1] + red[3] + red[5] + red[7];
  const float mean = s * (1.f / 1024.f);
  float var = (ss - s * mean) * (1.f / 1023.f);
  var = fmaxf(var, 0.f);
  const float k = al[0] / (sqrtf(var) + 1e-6f);
  const float g = be[0];
  ushort4 o;
  o.x = f2bf((v.x - mean) * k + g);
  o.y = f2bf((v.y - mean) * k + g);
  o.z = f2bf((v.z - mean) * k + g);
  o.w = f2bf((v.w - mean) * k + g);
  ((ushort4*)(out + (long)row * Dc))[tid] = o;
}

// ============ 256x256 GEMM, BK=64, 8 waves (2Mx4N), 4-phase fine interleave ============
template<int RELU, int OUTBF16, int RES, int VOUT>
__global__ __launch_bounds__(512, 2)
void gemm256(const unsigned short* __restrict__ A, const unsigned short* __restrict__ BT,
             const float* __restrict__ bias, const float* __restrict__ resid,
             void* __restrict__ Cout, unsigned short* __restrict__ vtw,
             int M, int N, int K){
  __shared__ unsigned short As[2][256 * 64];
  __shared__ unsigned short Bs[2][256 * 64];
  const int tid = threadIdx.x, wid = tid >> 6, lane = tid & 63;
  const int lg = lane >> 4, lr = lane & 15;
  const int wm = wid >> 2, wn = wid & 3;
  const int nwg = gridDim.x * gridDim.y;
  const int wg  = xcd_swz(blockIdx.y * gridDim.x + blockIdx.x, nwg);
  const int bx = wg % gridDim.x, by = wg / gridDim.x;
  const int m0 = by * 256, n0 = bx * 256;
  const long ldA = (long)K * 2;
  const f32x4 zero4 = {0.f, 0.f, 0.f, 0.f};
  f32x4 acc[8][4];
#pragma unroll
  for (int i = 0; i < 8; i++)
#pragma unroll
    for (int j = 0; j < 4; j++) acc[i][j] = zero4;

  auto stage_half = [&](int b, int kt, int h){
    const unsigned short* src = (h < 2) ? A : BT;
    const int rowg = ((h < 2) ? m0 : n0) + (h & 1) * 128;
    char* dst = ((h < 2) ? (char*)As[b] : (char*)Bs[b]) + (h & 1) * 16384;
#pragma unroll
    for (int l = 0; l < 2; ++l){
      const int ob = (wid*2 + l) * 1024;
      const int o  = ob + lane * 16;
      const int rr = o >> 7, c = (o >> 4) & 7;
      const long co = (long)kt * 128 + ((c ^ (rr & 7)) << 4);
      gload16((const char*)src + (long)(rowg + rr) * ldA + co, dst + ob);
    }
  };

  const int nt = K >> 6;
#pragma unroll
  for (int h = 0; h < 4; ++h) stage_half(0, 0, h);
  __syncthreads();   // tile 0 landed (prologue only)

  int cur = 0;
  for (int t = 0; t < nt; ++t){
    const char* as = (const char*)As[cur];
    const char* bs = (const char*)Bs[cur];
    bf16x8 bfr[4][2];
#pragma unroll
    for (int p = 0; p < 4; ++p){
      if (p == 0){
#pragma unroll
        for (int ni = 0; ni < 4; ++ni){
          const int row = wn*64 + ni*16 + lr;
#pragma unroll
          for (int ks = 0; ks < 2; ++ks)
            bfr[ni][ks] = *reinterpret_cast<const bf16x8*>(bs + row*128 + (((ks*4 + lg) ^ (row & 7)) << 4));
        }
      }
      bf16x8 af[2][2];
#pragma unroll
      for (int i = 0; i < 2; ++i){
        const int arow = wm*128 + (2*p + i)*16 + lr;
        af[i][0] = *reinterpret_cast<const bf16x8*>(as + arow*128 + (((0*4 + lg) ^ (arow & 7)) << 4));
        af[i][1] = *reinterpret_cast<const bf16x8*>(as + arow*128 + (((1*4 + lg) ^ (arow & 7)) << 4));
      }
      if (t + 1 < nt) stage_half(cur ^ 1, t + 1, p);
      __builtin_amdgcn_sched_barrier(0);
      __builtin_amdgcn_s_barrier();
      asm volatile("s_waitcnt lgkmcnt(0)" ::: "memory");
      __builtin_amdgcn_sched_barrier(0);
      __builtin_amdgcn_s_setprio(1);
#pragma unroll
      for (int i = 0; i < 2; ++i){
        const int mi = 2*p + i;
#pragma unroll
        for (int ni = 0; ni < 4; ++ni){
          acc[mi][ni] = mfma16(af[i][0], bfr[ni][0], acc[mi][ni]);
          acc[mi][ni] = mfma16(af[i][1], bfr[ni][1], acc[mi][ni]);
        }
      }
      __builtin_amdgcn_s_setprio(0);
      __builtin_amdgcn_sched_barrier(0);
      __builtin_amdgcn_s_barrier();
    }
    if (t + 1 < nt){
      asm volatile("s_waitcnt vmcnt(0)" ::: "memory");
      __builtin_amdgcn_s_barrier();
      __builtin_amdgcn_sched_barrier(0);
    }
    cur ^= 1;
  }

  if (VOUT && n0 >= 2048){
#pragma unroll
    for (int mi = 0; mi < 8; ++mi){
      const int row = m0 + wm*128 + mi*16 + lg*4;   // 4 consecutive rows (same batch)
      const int b = row >> 11, s = row & 2047;
#pragma unroll
      for (int ni = 0; ni < 4; ++ni){
        const int col = n0 + wn*64 + ni*16 + lr;
        const float bc = bias[col];
        ushort4 o;
        o.x = f2bf(acc[mi][ni][0] + bc);
        o.y = f2bf(acc[mi][ni][1] + bc);
        o.z = f2bf(acc[mi][ni][2] + bc);
        o.w = f2bf(acc[mi][ni][3] + bc);
        *(ushort4*)(vtw + ((long)(b * 1024 + (col - 2048)) << 11) + s) = o;
      }
    }
    return;
  }

#pragma unroll
  for (int mi = 0; mi < 8; ++mi)
#pragma unroll
    for (int ni = 0; ni < 4; ++ni){
      const int col = n0 + wn*64 + ni*16 + lr;
      const float bc = bias[col];
#pragma unroll
      for (int r = 0; r < 4; ++r){
        const int row = m0 + wm*128 + mi*16 + lg*4 + r;
        float v = acc[mi][ni][r] + bc;
        if (RES)  v += resid[(long)row * N + col];
        if (RELU) v = fmaxf(v, 0.f);
        if (OUTBF16) ((unsigned short*)Cout)[(long)row * N + col] = f2bf(v);
        else         ((float*)Cout)[(long)row * N + col] = v;
      }
    }
}

// ============ 128x64 GEMM, BK=64, 8 waves (4Mx2N, 32x32/wave), counted-vmcnt dbuf ============
template<int RELU, int OUTBF16, int RES>
__global__ __launch_bounds__(512, 2)
void gemm12864(const unsigned short* __restrict__ A, const unsigned short* __restrict__ BT,
               const float* __restrict__ bias, const float* __restrict__ resid,
               void* __restrict__ Cout, int M, int N, int K){
  __shared__ unsigned short As[2][128 * 64];
  __shared__ unsigned short Bs[2][64 * 64];
  const int tid = threadIdx.x, wid = tid >> 6, lane = tid & 63;
  const int lg = lane >> 4, lr = lane & 15;
  const int wm = wid >> 1, wn = wid & 1;
  const int nwg = gridDim.x * gridDim.y;
  const int wg  = xcd_swz(blockIdx.y * gridDim.x + blockIdx.x, nwg);
  const int bx = wg % gridDim.x, by = wg / gridDim.x;
  const int m0 = by * 128, n0 = bx * 64;
  const long ldA = (long)K * 2;
  const f32x4 zero4 = {0.f, 0.f, 0.f, 0.f};
  f32x4 acc[2][2];
#pragma unroll
  for (int i = 0; i < 2; i++)
#pragma unroll
    for (int j = 0; j < 2; j++) acc[i][j] = zero4;

  auto stage = [&](int b, int kt){      // 3 gload16 per wave (2 A-chunks + 1 B-chunk)
#pragma unroll
    for (int l = 0; l < 2; ++l){
      const int ob = (wid*2 + l) * 1024;     // A: 16KB = 16 chunks
      const int o  = ob + lane * 16;
      const int rr = o >> 7, c = (o >> 4) & 7;
      const long co = (long)kt * 128 + ((c ^ (rr & 7)) << 4);
      gload16((const char*)A + (long)(m0 + rr) * ldA + co, (char*)As[b] + ob);
    }
    {
      const int ob = wid * 1024;             // B: 8KB = 8 chunks
      const int o  = ob + lane * 16;
      const int rr = o >> 7, c = (o >> 4) & 7;
      const long co = (long)kt * 128 + ((c ^ (rr & 7)) << 4);
      gload16((const char*)BT + (long)(n0 + rr) * ldA + co, (char*)Bs[b] + ob);
    }
  };

  const int nt = K >> 6;
  stage(0, 0);
  stage(1, 1);

  int cur = 0;
  for (int t = 0; t < nt; ++t){
    if (t + 1 < nt) asm volatile("s_waitcnt vmcnt(3)" ::: "memory");
    else            asm volatile("s_waitcnt vmcnt(0)" ::: "memory");
    __builtin_amdgcn_s_barrier();
    __builtin_amdgcn_sched_barrier(0);
    const char* as = (const char*)As[cur];
    const char* bs = (const char*)Bs[cur];
    bf16x8 bfr[2][2];
#pragma unroll
    for (int ni = 0; ni < 2; ++ni){
      const int row = wn*32 + ni*16 + lr;
#pragma unroll
      for (int ks = 0; ks < 2; ++ks)
        bfr[ni][ks] = *reinterpret_cast<const bf16x8*>(bs + row*128 + (((ks*4 + lg) ^ (row & 7)) << 4));
    }
    __builtin_amdgcn_s_setprio(1);
#pragma unroll
    for (int mi = 0; mi < 2; ++mi){
      const int arow = wm*32 + mi*16 + lr;
      bf16x8 a0 = *reinterpret_cast<const bf16x8*>(as + arow*128 + (((0*4 + lg) ^ (arow & 7)) << 4));
      bf16x8 a1 = *reinterpret_cast<const bf16x8*>(as + arow*128 + (((1*4 + lg) ^ (arow & 7)) << 4));
#pragma unroll
      for (int ni = 0; ni < 2; ++ni){
        acc[mi][ni] = mfma16(a0, bfr[ni][0], acc[mi][ni]);
        acc[mi][ni] = mfma16(a1, bfr[ni][1], acc[mi][ni]);
      }
    }
    __builtin_amdgcn_s_setprio(0);
    __builtin_amdgcn_s_barrier();
    __builtin_amdgcn_sched_barrier(0);
    if (t + 2 < nt) stage(cur, t + 2);
    cur ^= 1;
  }

#pragma unroll
  for (int mi = 0; mi < 2; ++mi)
#pragma unroll
    for (int ni = 0; ni < 2; ++ni){
      const int col = n0 + wn*32 + ni*16 + lr;
      const float bc = bias[col];
#pragma unroll
      for (int r = 0; r < 4; ++r){
        const int row = m0 + wm*32 + mi*16 + lg*4 + r;
        float v = acc[mi][ni][r] + bc;
        if (RES)  v += resid[(long)row * N + col];
        if (RELU) v = fmaxf(v, 0.f);
        if (OUTBF16) ((unsigned short*)Cout)[(long)row * N + col] = f2bf(v);
        else         ((float*)Cout)[(long)row * N + col] = v;
      }
    }
}

// ---------- flash attention: QBLK=128 (8 waves), KVBLK=64, swapped QK^T ----------
// Qs/Ps UNION: Q is consumed into registers in the prologue; wave w's P strip
// occupies exactly the Q rows [16w,16w+16) that only wave w reads -> race-free.
// LDS = QP16 + K2x8 + V2x8 = 48KB -> 3 blocks/CU packable.
// bh-clustered XCD mapping; K/V double-buffered, single barrier per tile,
// issue-early staging; no running max; exp2-domain masked softmax; l via ones-MFMA.
__global__ __launch_bounds__(512)
void attn_k(const unsigned short* __restrict__ qkv, const unsigned short* __restrict__ vt,
            const float* __restrict__ madd, unsigned short* __restrict__ ctx){
  __shared__ unsigned short QP[128*64], Ks[2][64*64], Vs[2][64*64];
  const int tid = threadIdx.x, wid = tid >> 6, lane = tid & 63;
  const int lg = lane >> 4, lr = lane & 15;
  const int f   = blockIdx.y * gridDim.x + blockIdx.x;
  const int xcd = f & 7, j = f >> 3;
  const int bh  = (xcd << 2) | (j & 3);
  const int qt  = j >> 2;
  const int b = bh >> 4, h = bh & 15;
  const int s0 = qt * 128;
  const f32x4 zero4 = {0.f, 0.f, 0.f, 0.f};
  const short onebf = (short)0x3F80;
  const bf16x8 ones = {onebf, onebf, onebf, onebf, onebf, onebf, onebf, onebf};
  const float c1 = 0.18033688f;   // 0.125 * log2(e)

  const char* kbase = (const char*)qkv + (long)(b*Sc) * 6144 + 2048 + h * 128;
  const char* vbase = (const char*)vt + (long)bh * 64 * 4096;
  const float* mrow = madd + b * Sc;
  unsigned short* pb = QP + wid * 1024;   // wave-private 16x64 P strip = this wave's Q rows

  auto stageKV = [&](int t, int bsel){
    const int o = wid * 1024;
    const int ol = o + lane * 16;
    const int r = ol >> 7, c = (ol >> 4) & 7;
    const int sw = ((c ^ (r & 7)) << 4);
    gload16(kbase + (long)(t*64 + r) * 6144 + sw, (char*)Ks[bsel] + o);
    gload16(vbase + (long)r * 4096 + t*128 + sw, (char*)Vs[bsel] + o);
  };

  const char* qbase = (const char*)qkv + ((long)(b*Sc + s0)) * 6144 + h * 128;
#pragma unroll
  for (int ld = 0; ld < 2; ++ld){
    const int o = (wid*2 + ld) * 1024;
    const int ol = o + lane * 16;
    const int r = ol >> 7, c = (ol >> 4) & 7;
    gload16(qbase + (long)r * 6144 + ((c ^ (r & 7)) << 4), (char*)QP + o);
  }
  stageKV(0, 0);
  float4 ma[4];
#pragma unroll
  for (int ni = 0; ni < 4; ++ni) ma[ni] = *(const float4*)(mrow + ni*16 + lg*4);
  __syncthreads();
  // Q -> regs (each wave reads only its own rows wid*16..+15, which later become its P strip)
  bf16x8 qb[2];
#pragma unroll
  for (int ks = 0; ks < 2; ++ks){
    const int row = wid*16 + lr;
    qb[ks] = *reinterpret_cast<const bf16x8*>((const char*)QP + row*128 + (((ks*4 + lg) ^ (row & 7)) << 4));
  }

  f32x4 acc[4] = {zero4, zero4, zero4, zero4};
  f32x4 accS = zero4;
  constexpr int NT = Sc / 64;

  for (int t = 0; t < NT; ++t){
    if (t){
      asm volatile("s_waitcnt vmcnt(0)" ::: "memory");
      __builtin_amdgcn_s_barrier();
      __builtin_amdgcn_sched_barrier(0);
    }
    if (t + 1 < NT) stageKV(t + 1, (t + 1) & 1);
    float4 man[4];
    if (t + 1 < NT){
#pragma unroll
      for (int ni = 0; ni < 4; ++ni) man[ni] = *(const float4*)(mrow + (t+1)*64 + ni*16 + lg*4);
    }

    const int cur = t & 1;
    const char* ksb = (const char*)Ks[cur];
    const char* vsb = (const char*)Vs[cur];

    f32x4 s4[4];
    __builtin_amdgcn_s_setprio(1);
#pragma unroll
    for (int ni = 0; ni < 4; ++ni){
      s4[ni] = zero4;
      const int row = ni*16 + lr;
#pragma unroll
      for (int ks = 0; ks < 2; ++ks){
        bf16x8 ak = *reinterpret_cast<const bf16x8*>(ksb + row*128 + (((ks*4 + lg) ^ (lr & 7)) << 4));
        s4[ni] = mfma16(ak, qb[ks], s4[ni]);
      }
    }
    __builtin_amdgcn_s_setprio(0);

    float p[4][4];
#pragma unroll
    for (int ni = 0; ni < 4; ++ni){
      p[ni][0] = fexp2(fmaf(s4[ni][0], c1, ma[ni].x));
      p[ni][1] = fexp2(fmaf(s4[ni][1], c1, ma[ni].y));
      p[ni][2] = fexp2(fmaf(s4[ni][2], c1, ma[ni].z));
      p[ni][3] = fexp2(fmaf(s4[ni][3], c1, ma[ni].w));
    }

#pragma unroll
    for (int ni = 0; ni < 4; ++ni){
      uint2 w;
      w.x = pk2bf(p[ni][0], p[ni][1]);
      w.y = pk2bf(p[ni][2], p[ni][3]);
      const int c = ni*2 + (lg >> 1);
      char* dst = (char*)pb + lr*128 + ((c ^ (lr & 7)) << 4) + (lg & 1) * 8;
      *(uint2*)dst = w;
    }
    bf16x8 pa[2];
#pragma unroll
    for (int ks = 0; ks < 2; ++ks){
      pa[ks] = *reinterpret_cast<const bf16x8*>((const char*)pb + lr*128 + (((ks*4 + lg) ^ (lr & 7)) << 4));
    }
    __builtin_amdgcn_s_setprio(1);
#pragma unroll
    for (int ks = 0; ks < 2; ++ks) accS = mfma16(pa[ks], ones, accS);
#pragma unroll
    for (int ni = 0; ni < 4; ++ni){
      const int row = ni*16 + lr;
#pragma unroll
      for (int ks = 0; ks < 2; ++ks){
        bf16x8 bv8 = *reinterpret_cast<const bf16x8*>(vsb + row*128 + (((ks*4 + lg) ^ (lr & 7)) << 4));
        acc[ni] = mfma16(pa[ks], bv8, acc[ni]);
      }
    }
    __builtin_amdgcn_s_setprio(0);
    if (t + 1 < NT){
#pragma unroll
      for (int ni = 0; ni < 4; ++ni) ma[ni] = man[ni];
    }
  }
#pragma unroll
  for (int ni = 0; ni < 4; ++ni){
    const int col = h*64 + ni*16 + lr;
#pragma unroll
    for (int r = 0; r < 4; ++r){
      const int row = s0 + wid*16 + lg*4 + r;
      ctx[(long)(b*Sc + row) * Dc + col] = f2bf(acc[ni][r] / accS[r]);
    }
  }
}

// ---------- host ----------
extern "C" void kernel_launch(void* const* d_in, const int* in_sizes, int n_in,
                              void* d_out, int out_size, void* d_ws, size_t ws_size,
                              hipStream_t stream){
  const float* x  = (const float*)d_in[0];
  const int* mask = (const int*)d_in[1];
  const float* wq = (const float*)d_in[2];
  const float* bq = (const float*)d_in[3];
  const float* wk = (const float*)d_in[4];
  const float* bk = (const float*)d_in[5];
  const float* wv = (const float*)d_in[6];
  const float* bv = (const float*)d_in[7];
  const float* wo = (const float*)d_in[8];
  const float* bo = (const float*)d_in[9];
  const float* w1 = (const float*)d_in[10];
  const float* b1 = (const float*)d_in[11];
  const float* w2 = (const float*)d_in[12];
  const float* b2 = (const float*)d_in[13];
  const float* a1 = (const float*)d_in[14];
  const float* g1 = (const float*)d_in[15];
  const float* a2 = (const float*)d_in[16];
  const float* g2 = (const float*)d_in[17];

  if (ws_size < 75509760u) return;   // workspace layout below needs ~75.5 MB

  char* ws = (char*)d_ws;
  unsigned short* wqkv_t = (unsigned short*)(ws + 0);          // [3072][1024]
  unsigned short* wo_t   = (unsigned short*)(ws + 6291456);    // [1024][1024]
  unsigned short* w1_t   = (unsigned short*)(ws + 8388608);    // [4096][1024]
  unsigned short* w2_t   = (unsigned short*)(ws + 16777216);   // [1024][4096]
  float*          bqkv   = (float*)(ws + 25165824);            // [3072]
  unsigned short* nbuf   = (unsigned short*)(ws + 25178112);   // [4096][1024] (n1 then n2)
  float*          maddf  = (float*)(ws + 25178112);            // [2][2048] — aliases nbuf (dead during attn)
  unsigned short* qkv    = (unsigned short*)(ws + 33566720);   // [4096][3072] (V third unused)
  unsigned short* ff1    = (unsigned short*)(ws + 33566720);   // [4096][4096] (reuses qkv+vt)
  unsigned short* vt     = (unsigned short*)(ws + 58732544);   // [32][64][2048]
  unsigned short* ctx    = (unsigned short*)(ws + 67121152);   // [4096][1024]
  float* x2 = (float*)d_out;                                   // [4096][1024] f32

  prep_all<<<12300, 256, 0, stream>>>(wq, wk, wv, wo, w1, w2, bq, bk, bv,
                                      wqkv_t, wo_t, w1_t, w2_t, bqkv);

  layernorm_k<<<BSc, 256, 0, stream>>>(x, a1, g1, nbuf);
  gemm256<0,1,0,1><<<dim3(12, 16), 512, 0, stream>>>(nbuf, wqkv_t, bqkv, nullptr, qkv, vt, BSc, 3072, 1024);
  mask_addend<<<16, 256, 0, stream>>>(mask, maddf);   // nbuf dead from here until LN2
  attn_k<<<dim3(16, 32), 512, 0, stream>>>(qkv, vt, maddf, ctx);
  gemm12864<0,0,1><<<dim3(16, 32), 512, 0, stream>>>(ctx, wo_t, bo, x, x2, BSc, 1024, 1024);
  layernorm_k<<<BSc, 256, 0, stream>>>(x2, a2, g2, nbuf);
  gemm256<1,1,0,0><<<dim3(16, 16), 512, 0, stream>>>(nbuf, w1_t, b1, nullptr, ff1, nullptr, BSc, 4096, 1024);
  gemm12864<0,0,1><<<dim3(16, 32), 512, 0, stream>>>(ff1, w2_t, b2, x2, d_out, BSc, 1024, 4096);
}

// Round 21
// 213.601 us; speedup vs baseline: 1.0915x; 1.0328x over previous
//
#include <hip/hip_runtime.h>
#include <hip/hip_bf16.h>
#include <cstdint>

// ---------- problem constants ----------
constexpr int Bc  = 2;
constexpr int Sc  = 2048;
constexpr int Dc  = 1024;
constexpr int Hc  = 16;
constexpr int DKc = 64;
constexpr int DFFc= 4096;
constexpr int BSc = Bc * Sc;      // 4096 rows

typedef __attribute__((ext_vector_type(8))) short bf16x8;
typedef __attribute__((ext_vector_type(4))) float f32x4;

__device__ __forceinline__ unsigned short f2bf(float x){
  union { float f; uint32_t u; } v; v.f = x;
  uint32_t r = v.u + 0x7fffu + ((v.u >> 16) & 1u);   // RNE
  return (unsigned short)(r >> 16);
}

__device__ __forceinline__ void gload16(const void* g, void* l){
  __builtin_amdgcn_global_load_lds((const __attribute__((address_space(1))) void*)g,
                                   (__attribute__((address_space(3))) void*)l, 16, 0, 0);
}

__device__ __forceinline__ f32x4 mfma16(bf16x8 a, bf16x8 b, f32x4 c){
  return __builtin_amdgcn_mfma_f32_16x16x32_bf16(a, b, c, 0, 0, 0);
}

// pack two f32 -> one u32 of 2x bf16 (v_cvt_pk_bf16_f32)
__device__ __forceinline__ uint32_t pk2bf(float lo, float hi){
  __hip_bfloat162 h = __float22bfloat162_rn(make_float2(lo, hi));
  return *reinterpret_cast<uint32_t*>(&h);
}

// raw v_exp_f32: r = 2^x
__device__ __forceinline__ float fexp2(float x){
  float r; asm("v_exp_f32 %0, %1" : "=v"(r) : "v"(x)); return r;
}

// bijective XCD swizzle (T1, m204 form)
__device__ __forceinline__ int xcd_swz(int bid, int nwg){
  const int q = nwg >> 3, r = nwg & 7;
  const int xcd = bid & 7, idx = bid >> 3;
  return ((xcd < r) ? (xcd * (q + 1)) : (r * (q + 1) + (xcd - r) * q)) + idx;
}

// ---------- fused prep: 6 weight transposes + bias concat + LN1 ----------
// blocks 0-12287: weight transposes | 12288-12299: concat_bias | 12300-16395: LN1 rows
__global__ __launch_bounds__(256)
void prep_all(const float* __restrict__ wq, const float* __restrict__ wk,
              const float* __restrict__ wv, const float* __restrict__ wo,
              const float* __restrict__ w1, const float* __restrict__ w2,
              const float* __restrict__ bq, const float* __restrict__ bk,
              const float* __restrict__ bv,
              unsigned short* __restrict__ wqkv_t, unsigned short* __restrict__ wo_t,
              unsigned short* __restrict__ w1_t, unsigned short* __restrict__ w2_t,
              float* __restrict__ bqkv,
              const float* __restrict__ x, const float* __restrict__ al,
              const float* __restrict__ be, unsigned short* __restrict__ nbuf){
  const int id = blockIdx.x, tid = threadIdx.x;
  if (id >= 12300){                      // LN1: 4096 rows (ddof=1, eps on std)
    const int row = id - 12300;
    const float4 v = ((const float4*)(x + (long)row * Dc))[tid];
    float s  = v.x + v.y + v.z + v.w;
    float ss = v.x*v.x + v.y*v.y + v.z*v.z + v.w*v.w;
#pragma unroll
    for (int d = 1; d < 64; d <<= 1){ s += __shfl_xor(s, d, 64); ss += __shfl_xor(ss, d, 64); }
    __shared__ float red[8];
    const int wid = tid >> 6, lane = tid & 63;
    if (lane == 0){ red[wid*2] = s; red[wid*2+1] = ss; }
    __syncthreads();
    s  = red[0] + red[2] + red[4] + red[6];
    ss = red[1] + red[3] + red[5] + red[7];
    const float mean = s * (1.f / 1024.f);
    float var = (ss - s * mean) * (1.f / 1023.f);
    var = fmaxf(var, 0.f);
    const float k = al[0] / (sqrtf(var) + 1e-6f);
    const float g = be[0];
    ushort4 o;
    o.x = f2bf((v.x - mean) * k + g);
    o.y = f2bf((v.y - mean) * k + g);
    o.z = f2bf((v.z - mean) * k + g);
    o.w = f2bf((v.w - mean) * k + g);
    ((ushort4*)(nbuf + (long)row * Dc))[tid] = o;
    return;
  }
  if (id >= 12288){                      // concat_bias: 12 blocks x 256 = 3072
    const int i = (id - 12288) * 256 + tid;
    bqkv[i] = (i < 1024) ? bq[i] : (i < 2048 ? bk[i - 1024] : bv[i - 2048]);
    return;
  }
  const float* in; unsigned short* out; int K, N, bx, by;
  if (id < 4096){
    const int w = id >> 10, local = id & 1023;
    in  = (w == 0) ? wq : (w == 1) ? wk : (w == 2) ? wv : wo;
    out = (w == 0) ? wqkv_t : (w == 1) ? (wqkv_t + 1048576) : (w == 2) ? (wqkv_t + 2097152) : wo_t;
    K = 1024; N = 1024; bx = local & 31; by = local >> 5;
  } else if (id < 8192){
    const int local = id - 4096;
    in = w1; out = w1_t; K = 1024; N = 4096; bx = local & 127; by = local >> 7;
  } else {
    const int local = id - 8192;
    in = w2; out = w2_t; K = 4096; N = 1024; bx = local & 31; by = local >> 5;
  }
  __shared__ float t[32][33];
  const int tx = tid & 31, ty = tid >> 5;
  const int x0 = bx * 32, y0 = by * 32;
#pragma unroll
  for (int j = ty; j < 32; j += 8) t[j][tx] = in[(long)(y0 + j) * N + x0 + tx];
  __syncthreads();
#pragma unroll
  for (int j = ty; j < 32; j += 8)
    out[(long)(x0 + j) * K + y0 + tx] = f2bf(t[tx][j]);
}

// ---------- layernorm (ddof=1, eps on std, scalar alpha/beta) f32 -> bf16 ----------
__global__ __launch_bounds__(256)
void layernorm_k(const float* __restrict__ x, const float* __restrict__ al,
                 const float* __restrict__ be, unsigned short* __restrict__ out){
  const int row = blockIdx.x, tid = threadIdx.x;
  const float4 v = ((const float4*)(x + (long)row * Dc))[tid];
  float s  = v.x + v.y + v.z + v.w;
  float ss = v.x*v.x + v.y*v.y + v.z*v.z + v.w*v.w;
#pragma unroll
  for (int d = 1; d < 64; d <<= 1){ s += __shfl_xor(s, d, 64); ss += __shfl_xor(ss, d, 64); }
  __shared__ float red[8];
  const int wid = tid >> 6, lane = tid & 63;
  if (lane == 0){ red[wid*2] = s; red[wid*2+1] = ss; }
  __syncthreads();
  s  = red[0] + red[2] + red[4] + red[6];
  ss = red[1] + red[3] + red[5] + red[7];
  const float mean = s * (1.f / 1024.f);
  float var = (ss - s * mean) * (1.f / 1023.f);
  var = fmaxf(var, 0.f);
  const float k = al[0] / (sqrtf(var) + 1e-6f);
  const float g = be[0];
  ushort4 o;
  o.x = f2bf((v.x - mean) * k + g);
  o.y = f2bf((v.y - mean) * k + g);
  o.z = f2bf((v.z - mean) * k + g);
  o.w = f2bf((v.w - mean) * k + g);
  ((ushort4*)(out + (long)row * Dc))[tid] = o;
}

// ============ 256x256 GEMM, BK=64, 8 waves (2Mx4N), 4-phase fine interleave ============
template<int RELU, int OUTBF16, int RES, int VOUT>
__global__ __launch_bounds__(512, 2)
void gemm256(const unsigned short* __restrict__ A, const unsigned short* __restrict__ BT,
             const float* __restrict__ bias, const float* __restrict__ resid,
             void* __restrict__ Cout, unsigned short* __restrict__ vtw,
             int M, int N, int K){
  __shared__ unsigned short As[2][256 * 64];
  __shared__ unsigned short Bs[2][256 * 64];
  const int tid = threadIdx.x, wid = tid >> 6, lane = tid & 63;
  const int lg = lane >> 4, lr = lane & 15;
  const int wm = wid >> 2, wn = wid & 3;
  const int nwg = gridDim.x * gridDim.y;
  const int wg  = xcd_swz(blockIdx.y * gridDim.x + blockIdx.x, nwg);
  const int bx = wg % gridDim.x, by = wg / gridDim.x;
  const int m0 = by * 256, n0 = bx * 256;
  const long ldA = (long)K * 2;
  const f32x4 zero4 = {0.f, 0.f, 0.f, 0.f};
  f32x4 acc[8][4];
#pragma unroll
  for (int i = 0; i < 8; i++)
#pragma unroll
    for (int j = 0; j < 4; j++) acc[i][j] = zero4;

  auto stage_half = [&](int b, int kt, int h){
    const unsigned short* src = (h < 2) ? A : BT;
    const int rowg = ((h < 2) ? m0 : n0) + (h & 1) * 128;
    char* dst = ((h < 2) ? (char*)As[b] : (char*)Bs[b]) + (h & 1) * 16384;
#pragma unroll
    for (int l = 0; l < 2; ++l){
      const int ob = (wid*2 + l) * 1024;
      const int o  = ob + lane * 16;
      const int rr = o >> 7, c = (o >> 4) & 7;
      const long co = (long)kt * 128 + ((c ^ (rr & 7)) << 4);
      gload16((const char*)src + (long)(rowg + rr) * ldA + co, dst + ob);
    }
  };

  const int nt = K >> 6;
#pragma unroll
  for (int h = 0; h < 4; ++h) stage_half(0, 0, h);
  __syncthreads();   // tile 0 landed (prologue only)

  int cur = 0;
  for (int t = 0; t < nt; ++t){
    const char* as = (const char*)As[cur];
    const char* bs = (const char*)Bs[cur];
    bf16x8 bfr[4][2];
#pragma unroll
    for (int p = 0; p < 4; ++p){
      if (p == 0){
#pragma unroll
        for (int ni = 0; ni < 4; ++ni){
          const int row = wn*64 + ni*16 + lr;
#pragma unroll
          for (int ks = 0; ks < 2; ++ks)
            bfr[ni][ks] = *reinterpret_cast<const bf16x8*>(bs + row*128 + (((ks*4 + lg) ^ (row & 7)) << 4));
        }
      }
      bf16x8 af[2][2];
#pragma unroll
      for (int i = 0; i < 2; ++i){
        const int arow = wm*128 + (2*p + i)*16 + lr;
        af[i][0] = *reinterpret_cast<const bf16x8*>(as + arow*128 + (((0*4 + lg) ^ (arow & 7)) << 4));
        af[i][1] = *reinterpret_cast<const bf16x8*>(as + arow*128 + (((1*4 + lg) ^ (arow & 7)) << 4));
      }
      if (t + 1 < nt) stage_half(cur ^ 1, t + 1, p);
      __builtin_amdgcn_sched_barrier(0);
      __builtin_amdgcn_s_barrier();
      asm volatile("s_waitcnt lgkmcnt(0)" ::: "memory");
      __builtin_amdgcn_sched_barrier(0);
      __builtin_amdgcn_s_setprio(1);
#pragma unroll
      for (int i = 0; i < 2; ++i){
        const int mi = 2*p + i;
#pragma unroll
        for (int ni = 0; ni < 4; ++ni){
          acc[mi][ni] = mfma16(af[i][0], bfr[ni][0], acc[mi][ni]);
          acc[mi][ni] = mfma16(af[i][1], bfr[ni][1], acc[mi][ni]);
        }
      }
      __builtin_amdgcn_s_setprio(0);
      __builtin_amdgcn_sched_barrier(0);
      __builtin_amdgcn_s_barrier();
    }
    if (t + 1 < nt){
      asm volatile("s_waitcnt vmcnt(0)" ::: "memory");
      __builtin_amdgcn_s_barrier();
      __builtin_amdgcn_sched_barrier(0);
    }
    cur ^= 1;
  }

  if (VOUT && n0 >= 2048){
#pragma unroll
    for (int mi = 0; mi < 8; ++mi){
      const int row = m0 + wm*128 + mi*16 + lg*4;   // 4 consecutive rows (same batch)
      const int b = row >> 11, s = row & 2047;
#pragma unroll
      for (int ni = 0; ni < 4; ++ni){
        const int col = n0 + wn*64 + ni*16 + lr;
        const float bc = bias[col];
        ushort4 o;
        o.x = f2bf(acc[mi][ni][0] + bc);
        o.y = f2bf(acc[mi][ni][1] + bc);
        o.z = f2bf(acc[mi][ni][2] + bc);
        o.w = f2bf(acc[mi][ni][3] + bc);
        *(ushort4*)(vtw + ((long)(b * 1024 + (col - 2048)) << 11) + s) = o;
      }
    }
    return;
  }

#pragma unroll
  for (int mi = 0; mi < 8; ++mi)
#pragma unroll
    for (int ni = 0; ni < 4; ++ni){
      const int col = n0 + wn*64 + ni*16 + lr;
      const float bc = bias[col];
#pragma unroll
      for (int r = 0; r < 4; ++r){
        const int row = m0 + wm*128 + mi*16 + lg*4 + r;
        float v = acc[mi][ni][r] + bc;
        if (RES)  v += resid[(long)row * N + col];
        if (RELU) v = fmaxf(v, 0.f);
        if (OUTBF16) ((unsigned short*)Cout)[(long)row * N + col] = f2bf(v);
        else         ((float*)Cout)[(long)row * N + col] = v;
      }
    }
}

// ============ 128x64 GEMM, BK=64, 8 waves (4Mx2N, 32x32/wave), counted-vmcnt dbuf ============
template<int RELU, int OUTBF16, int RES>
__global__ __launch_bounds__(512, 2)
void gemm12864(const unsigned short* __restrict__ A, const unsigned short* __restrict__ BT,
               const float* __restrict__ bias, const float* __restrict__ resid,
               void* __restrict__ Cout, int M, int N, int K){
  __shared__ unsigned short As[2][128 * 64];
  __shared__ unsigned short Bs[2][64 * 64];
  const int tid = threadIdx.x, wid = tid >> 6, lane = tid & 63;
  const int lg = lane >> 4, lr = lane & 15;
  const int wm = wid >> 1, wn = wid & 1;
  const int nwg = gridDim.x * gridDim.y;
  const int wg  = xcd_swz(blockIdx.y * gridDim.x + blockIdx.x, nwg);
  const int bx = wg % gridDim.x, by = wg / gridDim.x;
  const int m0 = by * 128, n0 = bx * 64;
  const long ldA = (long)K * 2;
  const f32x4 zero4 = {0.f, 0.f, 0.f, 0.f};
  f32x4 acc[2][2];
#pragma unroll
  for (int i = 0; i < 2; i++)
#pragma unroll
    for (int j = 0; j < 2; j++) acc[i][j] = zero4;

  auto stage = [&](int b, int kt){      // 3 gload16 per wave (2 A-chunks + 1 B-chunk)
#pragma unroll
    for (int l = 0; l < 2; ++l){
      const int ob = (wid*2 + l) * 1024;     // A: 16KB = 16 chunks
      const int o  = ob + lane * 16;
      const int rr = o >> 7, c = (o >> 4) & 7;
      const long co = (long)kt * 128 + ((c ^ (rr & 7)) << 4);
      gload16((const char*)A + (long)(m0 + rr) * ldA + co, (char*)As[b] + ob);
    }
    {
      const int ob = wid * 1024;             // B: 8KB = 8 chunks
      const int o  = ob + lane * 16;
      const int rr = o >> 7, c = (o >> 4) & 7;
      const long co = (long)kt * 128 + ((c ^ (rr & 7)) << 4);
      gload16((const char*)BT + (long)(n0 + rr) * ldA + co, (char*)Bs[b] + ob);
    }
  };

  const int nt = K >> 6;
  stage(0, 0);
  stage(1, 1);

  int cur = 0;
  for (int t = 0; t < nt; ++t){
    if (t + 1 < nt) asm volatile("s_waitcnt vmcnt(3)" ::: "memory");
    else            asm volatile("s_waitcnt vmcnt(0)" ::: "memory");
    __builtin_amdgcn_s_barrier();
    __builtin_amdgcn_sched_barrier(0);
    const char* as = (const char*)As[cur];
    const char* bs = (const char*)Bs[cur];
    bf16x8 bfr[2][2];
#pragma unroll
    for (int ni = 0; ni < 2; ++ni){
      const int row = wn*32 + ni*16 + lr;
#pragma unroll
      for (int ks = 0; ks < 2; ++ks)
        bfr[ni][ks] = *reinterpret_cast<const bf16x8*>(bs + row*128 + (((ks*4 + lg) ^ (row & 7)) << 4));
    }
    __builtin_amdgcn_s_setprio(1);
#pragma unroll
    for (int mi = 0; mi < 2; ++mi){
      const int arow = wm*32 + mi*16 + lr;
      bf16x8 a0 = *reinterpret_cast<const bf16x8*>(as + arow*128 + (((0*4 + lg) ^ (arow & 7)) << 4));
      bf16x8 a1 = *reinterpret_cast<const bf16x8*>(as + arow*128 + (((1*4 + lg) ^ (arow & 7)) << 4));
#pragma unroll
      for (int ni = 0; ni < 2; ++ni){
        acc[mi][ni] = mfma16(a0, bfr[ni][0], acc[mi][ni]);
        acc[mi][ni] = mfma16(a1, bfr[ni][1], acc[mi][ni]);
      }
    }
    __builtin_amdgcn_s_setprio(0);
    __builtin_amdgcn_s_barrier();
    __builtin_amdgcn_sched_barrier(0);
    if (t + 2 < nt) stage(cur, t + 2);
    cur ^= 1;
  }

#pragma unroll
  for (int mi = 0; mi < 2; ++mi)
#pragma unroll
    for (int ni = 0; ni < 2; ++ni){
      const int col = n0 + wn*32 + ni*16 + lr;
      const float bc = bias[col];
#pragma unroll
      for (int r = 0; r < 4; ++r){
        const int row = m0 + wm*32 + mi*16 + lg*4 + r;
        float v = acc[mi][ni][r] + bc;
        if (RES)  v += resid[(long)row * N + col];
        if (RELU) v = fmaxf(v, 0.f);
        if (OUTBF16) ((unsigned short*)Cout)[(long)row * N + col] = f2bf(v);
        else         ((float*)Cout)[(long)row * N + col] = v;
      }
    }
}

// ---------- flash attention: QBLK=128 (8 waves), KVBLK=64, swapped QK^T ----------
// Qs/Ps UNION; mask converted once in prologue into an 8KB LDS table (broadcast
// reads per tile, conflict-free) -> no separate mask_addend kernel.
// LDS = QP16 + K2x8 + V2x8 + MAD8 = 56KB (grid-capped at 2 blocks/CU anyway).
// bh-clustered XCD mapping; K/V dbuf, single barrier per tile, issue-early staging;
// no running max; exp2-domain masked softmax; l via ones-MFMA.
__global__ __launch_bounds__(512)
void attn_k(const unsigned short* __restrict__ qkv, const unsigned short* __restrict__ vt,
            const int* __restrict__ mask, unsigned short* __restrict__ ctx){
  __shared__ unsigned short QP[128*64], Ks[2][64*64], Vs[2][64*64];
  __shared__ float MAD[2048];
  const int tid = threadIdx.x, wid = tid >> 6, lane = tid & 63;
  const int lg = lane >> 4, lr = lane & 15;
  const int f   = blockIdx.y * gridDim.x + blockIdx.x;
  const int xcd = f & 7, j = f >> 3;
  const int bh  = (xcd << 2) | (j & 3);
  const int qt  = j >> 2;
  const int b = bh >> 4, h = bh & 15;
  const int s0 = qt * 128;
  const f32x4 zero4 = {0.f, 0.f, 0.f, 0.f};
  const short onebf = (short)0x3F80;
  const bf16x8 ones = {onebf, onebf, onebf, onebf, onebf, onebf, onebf, onebf};
  const float c1 = 0.18033688f;   // 0.125 * log2(e)

  const char* kbase = (const char*)qkv + (long)(b*Sc) * 6144 + 2048 + h * 128;
  const char* vbase = (const char*)vt + (long)bh * 64 * 4096;
  unsigned short* pb = QP + wid * 1024;   // wave-private 16x64 P strip = this wave's Q rows

  auto stageKV = [&](int t, int bsel){
    const int o = wid * 1024;
    const int ol = o + lane * 16;
    const int r = ol >> 7, c = (ol >> 4) & 7;
    const int sw = ((c ^ (r & 7)) << 4);
    gload16(kbase + (long)(t*64 + r) * 6144 + sw, (char*)Ks[bsel] + o);
    gload16(vbase + (long)r * 4096 + t*128 + sw, (char*)Vs[bsel] + o);
  };

  const char* qbase = (const char*)qkv + ((long)(b*Sc + s0)) * 6144 + h * 128;
#pragma unroll
  for (int ld = 0; ld < 2; ++ld){
    const int o = (wid*2 + ld) * 1024;
    const int ol = o + lane * 16;
    const int r = ol >> 7, c = (ol >> 4) & 7;
    gload16(qbase + (long)r * 6144 + ((c ^ (r & 7)) << 4), (char*)QP + o);
  }
  stageKV(0, 0);
  // mask -> exp2-domain addend table (once): 512 threads x int4 = 2048 entries
  {
    const int4 m4 = *(const int4*)(mask + b * Sc + tid * 4);
    float4 fm;
    fm.x = (m4.x != 0) ? 0.f : -1.442695e9f;
    fm.y = (m4.y != 0) ? 0.f : -1.442695e9f;
    fm.z = (m4.z != 0) ? 0.f : -1.442695e9f;
    fm.w = (m4.w != 0) ? 0.f : -1.442695e9f;
    *(float4*)&MAD[tid * 4] = fm;
  }
  __syncthreads();
  // Q -> regs (each wave reads only its own rows wid*16..+15, which later become its P strip)
  bf16x8 qb[2];
#pragma unroll
  for (int ks = 0; ks < 2; ++ks){
    const int row = wid*16 + lr;
    qb[ks] = *reinterpret_cast<const bf16x8*>((const char*)QP + row*128 + (((ks*4 + lg) ^ (row & 7)) << 4));
  }

  f32x4 acc[4] = {zero4, zero4, zero4, zero4};
  f32x4 accS = zero4;
  constexpr int NT = Sc / 64;

  for (int t = 0; t < NT; ++t){
    if (t){
      asm volatile("s_waitcnt vmcnt(0)" ::: "memory");
      __builtin_amdgcn_s_barrier();
      __builtin_amdgcn_sched_barrier(0);
    }
    if (t + 1 < NT) stageKV(t + 1, (t + 1) & 1);

    const int cur = t & 1;
    const int k0 = t * 64;
    const char* ksb = (const char*)Ks[cur];
    const char* vsb = (const char*)Vs[cur];

    f32x4 s4[4];
    __builtin_amdgcn_s_setprio(1);
#pragma unroll
    for (int ni = 0; ni < 4; ++ni){
      s4[ni] = zero4;
      const int row = ni*16 + lr;
#pragma unroll
      for (int ks = 0; ks < 2; ++ks){
        bf16x8 ak = *reinterpret_cast<const bf16x8*>(ksb + row*128 + (((ks*4 + lg) ^ (lr & 7)) << 4));
        s4[ni] = mfma16(ak, qb[ks], s4[ni]);
      }
    }
    __builtin_amdgcn_s_setprio(0);

    float p[4][4];
#pragma unroll
    for (int ni = 0; ni < 4; ++ni){
      const float4 ma = *(const float4*)&MAD[k0 + ni*16 + lg*4];   // broadcast read
      p[ni][0] = fexp2(fmaf(s4[ni][0], c1, ma.x));
      p[ni][1] = fexp2(fmaf(s4[ni][1], c1, ma.y));
      p[ni][2] = fexp2(fmaf(s4[ni][2], c1, ma.z));
      p[ni][3] = fexp2(fmaf(s4[ni][3], c1, ma.w));
    }

#pragma unroll
    for (int ni = 0; ni < 4; ++ni){
      uint2 w;
      w.x = pk2bf(p[ni][0], p[ni][1]);
      w.y = pk2bf(p[ni][2], p[ni][3]);
      const int c = ni*2 + (lg >> 1);
      char* dst = (char*)pb + lr*128 + ((c ^ (lr & 7)) << 4) + (lg & 1) * 8;
      *(uint2*)dst = w;
    }
    bf16x8 pa[2];
#pragma unroll
    for (int ks = 0; ks < 2; ++ks){
      pa[ks] = *reinterpret_cast<const bf16x8*>((const char*)pb + lr*128 + (((ks*4 + lg) ^ (lr & 7)) << 4));
    }
    __builtin_amdgcn_s_setprio(1);
#pragma unroll
    for (int ks = 0; ks < 2; ++ks) accS = mfma16(pa[ks], ones, accS);
#pragma unroll
    for (int ni = 0; ni < 4; ++ni){
      const int row = ni*16 + lr;
#pragma unroll
      for (int ks = 0; ks < 2; ++ks){
        bf16x8 bv8 = *reinterpret_cast<const bf16x8*>(vsb + row*128 + (((ks*4 + lg) ^ (lr & 7)) << 4));
        acc[ni] = mfma16(pa[ks], bv8, acc[ni]);
      }
    }
    __builtin_amdgcn_s_setprio(0);
  }
#pragma unroll
  for (int ni = 0; ni < 4; ++ni){
    const int col = h*64 + ni*16 + lr;
#pragma unroll
    for (int r = 0; r < 4; ++r){
      const int row = s0 + wid*16 + lg*4 + r;
      ctx[(long)(b*Sc + row) * Dc + col] = f2bf(acc[ni][r] / accS[r]);
    }
  }
}

// ---------- host ----------
extern "C" void kernel_launch(void* const* d_in, const int* in_sizes, int n_in,
                              void* d_out, int out_size, void* d_ws, size_t ws_size,
                              hipStream_t stream){
  const float* x  = (const float*)d_in[0];
  const int* mask = (const int*)d_in[1];
  const float* wq = (const float*)d_in[2];
  const float* bq = (const float*)d_in[3];
  const float* wk = (const float*)d_in[4];
  const float* bk = (const float*)d_in[5];
  const float* wv = (const float*)d_in[6];
  const float* bv = (const float*)d_in[7];
  const float* wo = (const float*)d_in[8];
  const float* bo = (const float*)d_in[9];
  const float* w1 = (const float*)d_in[10];
  const float* b1 = (const float*)d_in[11];
  const float* w2 = (const float*)d_in[12];
  const float* b2 = (const float*)d_in[13];
  const float* a1 = (const float*)d_in[14];
  const float* g1 = (const float*)d_in[15];
  const float* a2 = (const float*)d_in[16];
  const float* g2 = (const float*)d_in[17];

  if (ws_size < 75509760u) return;   // workspace layout below needs ~75.5 MB

  char* ws = (char*)d_ws;
  unsigned short* wqkv_t = (unsigned short*)(ws + 0);          // [3072][1024]
  unsigned short* wo_t   = (unsigned short*)(ws + 6291456);    // [1024][1024]
  unsigned short* w1_t   = (unsigned short*)(ws + 8388608);    // [4096][1024]
  unsigned short* w2_t   = (unsigned short*)(ws + 16777216);   // [1024][4096]
  float*          bqkv   = (float*)(ws + 25165824);            // [3072]
  unsigned short* nbuf   = (unsigned short*)(ws + 25178112);   // [4096][1024] (n1 then n2)
  unsigned short* qkv    = (unsigned short*)(ws + 33566720);   // [4096][3072] (V third unused)
  unsigned short* ff1    = (unsigned short*)(ws + 33566720);   // [4096][4096] (reuses qkv+vt)
  unsigned short* vt     = (unsigned short*)(ws + 58732544);   // [32][64][2048]
  unsigned short* ctx    = (unsigned short*)(ws + 67121152);   // [4096][1024]
  float* x2 = (float*)d_out;                                   // [4096][1024] f32

  prep_all<<<16396, 256, 0, stream>>>(wq, wk, wv, wo, w1, w2, bq, bk, bv,
                                      wqkv_t, wo_t, w1_t, w2_t, bqkv,
                                      x, a1, g1, nbuf);

  gemm256<0,1,0,1><<<dim3(12, 16), 512, 0, stream>>>(nbuf, wqkv_t, bqkv, nullptr, qkv, vt, BSc, 3072, 1024);
  attn_k<<<dim3(16, 32), 512, 0, stream>>>(qkv, vt, mask, ctx);
  gemm12864<0,0,1><<<dim3(16, 32), 512, 0, stream>>>(ctx, wo_t, bo, x, x2, BSc, 1024, 1024);
  layernorm_k<<<BSc, 256, 0, stream>>>(x2, a2, g2, nbuf);
  gemm256<1,1,0,0><<<dim3(16, 16), 512, 0, stream>>>(nbuf, w1_t, b1, nullptr, ff1, nullptr, BSc, 4096, 1024);
  gemm12864<0,0,1><<<dim3(16, 32), 512, 0, stream>>>(ff1, w2_t, b2, x2, d_out, BSc, 1024, 4096);
}